// Round 7
// baseline (261.105 us; speedup 1.0000x reference)
//
#include <hip/hip_runtime.h>
#include <stdint.h>

// B=16, C=64, H=128, W=128, HX=HY=64. All I/O fp32.
// Pipeline (3 kernels):
//   k_proj0 : pre_x[t=w][seq=(b,h)][j] (f16, incl bias) = Wihx·x + b   (bf16 hi/lo, unchanged)
//   k_scan<0>: X recurrence; FUSED Y-projection -> pre_y[t=h][seq=(b,w)][j] (f16, incl bias)
//   k_scan<1>: Y recurrence -> out[b][j][h][w] fp32
// d_ws: pre_x (33.5MB) + pre_y (33.5MB) = 67MB.
// ROUND 7: BARRIER-FREE SINGLE-WAVE CHAIN. Round 6 showed PASS0 (4 MFMA) and
// PASS1 (2 MFMA) both at 388ns/step -> the tick is the cross-wave exchange
// (ds_write + __syncthreads + ds_read), not the work. Fix: one wave owns the
// whole chain (16 seqs x 64 j = 4 m-tiles). The C->B handoff becomes FREE via
// a row permutation of Whh/Wy: with
//     j'(mt, m) = (mt&1)*32 + (m>>2)*8 + (mt>>1)*4 + (m&3)
// lane (l15=seq, q) C-slot (mt, r) holds unit j' = (mt&1)*32 + q*8 + (mt>>1)*4 + r,
// which is exactly B-element (kc=mt&1, i=(mt>>1)*4+r) = k-position kc*32+q*8+i = j'.
// So Bf[mt&1][(mt>>1)*4+r] = (f16)tanh(C[mt][r]) -- no LDS, no barrier, no
// shuffle. The permutation telescopes to identity on the contraction index
// (B holds h[j=k] at position k), and is absorbed into A/Y row loads, bias,
// pre/prey/out addressing. All lane layouts (A: m=l15,k=q*8+i; B: n=l15,
// k=q*8+i; C: n=l15,m=q*4+r) are the ones proven by the round-6 kernel.
// No drain points -> prey/out stores go in-loop; pre slab double-buffered in
// registers (psA/psB named, static indexing). 128 chains x 1 wave.

#define TLEN 128
#define NSEQ 2048
#define PSH (NSEQ*64)   // f16 elems per t-slice

typedef __bf16   bf16x8 __attribute__((ext_vector_type(8)));
typedef _Float16 f16x8  __attribute__((ext_vector_type(8)));
typedef _Float16 f16x4  __attribute__((ext_vector_type(4)));
typedef float    f32x4  __attribute__((ext_vector_type(4)));
typedef unsigned short u16x4 __attribute__((ext_vector_type(4)));

static __device__ __forceinline__ unsigned int fbits(float f){
    union { float f; unsigned int u; } v; v.f = f; return v.u;
}
static __device__ __forceinline__ float ubits(unsigned int u){
    union { unsigned int u; float f; } v; v.u = u; return v.f;
}
static __device__ __forceinline__ float bf2f(unsigned short s){ return ubits(((unsigned int)s) << 16); }
static __device__ __forceinline__ unsigned short f2bf(float f){
    unsigned int u = fbits(f);
    return (unsigned short)((u + 0x7FFFu + ((u >> 16) & 1u)) >> 16);
}
static __device__ __forceinline__ __bf16 us2b(unsigned short s){
    union { unsigned short u; __bf16 b; } v; v.u = s; return v.b;
}
static __device__ __forceinline__ unsigned short h2us(_Float16 h){
    union { _Float16 h; unsigned short s; } v; v.h = h; return v.s;
}
struct bfpair { __bf16 hi, lo; };
static __device__ __forceinline__ bfpair splitf(float f){   // RNE split (weights, once)
    unsigned short h = f2bf(f);
    bfpair r; r.hi = us2b(h); r.lo = us2b(f2bf(f - bf2f(h))); return r;
}
static __device__ __forceinline__ float fast_tanh(float x){
    float e = __builtin_amdgcn_exp2f(x * 2.8853900817779268f);
    return 1.0f - 2.0f * __builtin_amdgcn_rcpf(e + 1.0f);
}

// ---------------------------------------------------------------------------
// k_proj0: pre_x[w][b*128+h][j] = f16( sum_c x[b][c][h][w]*Wihx[j][c] + bias )
// bf16 hi/lo 3-term MFMA. Block 256thr/4 waves; wave: 32 rows x 64 j.
__global__ __launch_bounds__(256) void k_proj0(const float* __restrict__ A,
                                               const float* __restrict__ Wih,
                                               const float* __restrict__ b1,
                                               const float* __restrict__ b2,
                                               _Float16* __restrict__ pre){
    int lane = threadIdx.x & 63;
    int wv   = threadIdx.x >> 6;
    int q    = lane >> 4, l15 = lane & 15;

    bf16x8 Whi[4][2], Wlo[4][2];
#pragma unroll
    for (int n = 0; n < 4; n++)
#pragma unroll
        for (int kc = 0; kc < 2; kc++){
            const float* p = Wih + (n * 16 + l15) * 64 + kc * 32 + q * 8;
#pragma unroll
            for (int i = 0; i < 8; i++){
                bfpair s = splitf(p[i]);
                Whi[n][kc][i] = s.hi; Wlo[n][kc][i] = s.lo;
            }
        }
    float bias[4];
#pragma unroll
    for (int n = 0; n < 4; n++){
        int j = n * 16 + l15;
        bias[n] = b1[j] + b2[j];
    }

    int row0 = blockIdx.x * 128 + wv * 32;

    float av[2][2][8];
#pragma unroll
    for (int mi = 0; mi < 2; mi++){
        int r = row0 + mi * 16 + l15;
        int b = r >> 14, hw = r & 16383;
        const float* xb = A + (size_t)b * 1048576 + hw;
#pragma unroll
        for (int kc = 0; kc < 2; kc++)
#pragma unroll
            for (int i = 0; i < 8; i++)
                av[mi][kc][i] = xb[(size_t)(kc * 32 + q * 8 + i) * 16384];
    }

#pragma unroll
    for (int mi = 0; mi < 2; mi++){
        int rb = row0 + mi * 16;
        bf16x8 Ahi[2], Alo[2];
#pragma unroll
        for (int kc = 0; kc < 2; kc++)
#pragma unroll
            for (int i = 0; i < 8; i++){
                bfpair s = splitf(av[mi][kc][i]);
                Ahi[kc][i] = s.hi; Alo[kc][i] = s.lo;
            }
        f32x4 acc[4];
#pragma unroll
        for (int n = 0; n < 4; n++) acc[n] = (f32x4){bias[n], bias[n], bias[n], bias[n]};
#pragma unroll
        for (int n = 0; n < 4; n++)
#pragma unroll
            for (int kc = 0; kc < 2; kc++){
                acc[n] = __builtin_amdgcn_mfma_f32_16x16x32_bf16(Ahi[kc], Whi[n][kc], acc[n], 0, 0, 0);
                acc[n] = __builtin_amdgcn_mfma_f32_16x16x32_bf16(Alo[kc], Whi[n][kc], acc[n], 0, 0, 0);
                acc[n] = __builtin_amdgcn_mfma_f32_16x16x32_bf16(Ahi[kc], Wlo[n][kc], acc[n], 0, 0, 0);
            }
        // rows rb..rb+15 share (b,h); w = (rb&127) + q*4 + rr. seq_x = b*128+h.
        int bT = rb >> 14, hT = (rb >> 7) & 127, wBase = rb & 127;
        size_t seqOff = (size_t)bT * 128 + hT;
#pragma unroll
        for (int n = 0; n < 4; n++)
#pragma unroll
            for (int rr = 0; rr < 4; rr++){
                int w = wBase + q * 4 + rr;
                pre[((size_t)w * NSEQ + seqOff) * 64 + n * 16 + l15] = (_Float16)acc[n][rr];
            }
    }
}

// ---------------------------------------------------------------------------
// k_scan<PASS>: h_t = tanh(pre_t + Whh h_{t-1}), 128 blocks x 1 wave (64 thr).
// One wave owns one 16-seq chain entirely: 4 m-tiles (permuted rows), 2 k-
// chunks. No LDS, no barriers. Per step: a-init cvt, 8 rec MFMA (4 indep
// 2-chains), (PASS0) 8 Y MFMA + prey u16x4 stores, 16x tanh, f16 pack
// directly into next-step B fragments. pre slab double-buffered (psA/psB,
// 4 steps each, all static indexing).
// PASS 0: fused Y-proj on h_{t-1} -> pre_y[t-1] f16 (incl bias_y) + tail.
// PASS 1: final out[b][j][t][w] fp32, stored in-loop (no drain points).

#define JST(mt) ((((mt) & 1) * 32) + (q * 8) + (((mt) >> 1) * 4))

#define LOADSLAB(PS, TBASE)                                                     \
    _Pragma("unroll")                                                           \
    for (int u_ = 0; u_ < 4; u_++)                                              \
        _Pragma("unroll")                                                       \
        for (int mt_ = 0; mt_ < 4; mt_++)                                       \
            PS[u_][mt_] = *(const f16x4*)(pb + (size_t)((TBASE) + u_) * PSH + JST(mt_));

#define STEP4(PS, TBASE)                                                        \
    _Pragma("unroll")                                                           \
    for (int u = 0; u < 4; u++){                                                \
        int t = (TBASE) + u;                                                    \
        f32x4 a[4];                                                             \
        _Pragma("unroll")                                                       \
        for (int mt = 0; mt < 4; mt++){                                         \
            a[mt] = (f32x4){(float)PS[u][mt][0], (float)PS[u][mt][1],           \
                            (float)PS[u][mt][2], (float)PS[u][mt][3]};          \
            a[mt] = __builtin_amdgcn_mfma_f32_16x16x32_f16(Af[mt][0], Bf0, a[mt], 0, 0, 0); \
            a[mt] = __builtin_amdgcn_mfma_f32_16x16x32_f16(Af[mt][1], Bf1, a[mt], 0, 0, 0); \
        }                                                                       \
        if constexpr (PASS == 0){                                               \
            _Pragma("unroll")                                                   \
            for (int mt = 0; mt < 4; mt++){                                     \
                f32x4 y = biasy[mt];                                            \
                y = __builtin_amdgcn_mfma_f32_16x16x32_f16(Yf[mt][0], Bf0, y, 0, 0, 0); \
                y = __builtin_amdgcn_mfma_f32_16x16x32_f16(Yf[mt][1], Bf1, y, 0, 0, 0); \
                u16x4 pv;                                                       \
                _Pragma("unroll")                                               \
                for (int r = 0; r < 4; r++) pv[r] = h2us((_Float16)y[r]);       \
                if (t > 0)                                                      \
                    *(u16x4*)(prey + (spy + (size_t)(t - 1)) * 64 + JST(mt)) = pv; \
            }                                                                   \
        }                                                                       \
        f16x8 nB0, nB1;                                                         \
        _Pragma("unroll")                                                       \
        for (int mt = 0; mt < 4; mt++)                                          \
            _Pragma("unroll")                                                   \
            for (int r = 0; r < 4; r++){                                        \
                float tv = fast_tanh(a[mt][r]);                                 \
                if constexpr (PASS == 1)                                        \
                    outf[((size_t)(bb * 64 + JST(mt) + r) * TLEN + t) * 128 + low7 + l15] = tv; \
                if ((mt & 1) == 0) nB0[((mt >> 1) * 4) + r] = (_Float16)tv;     \
                else               nB1[((mt >> 1) * 4) + r] = (_Float16)tv;     \
            }                                                                   \
        Bf0 = nB0; Bf1 = nB1;                                                   \
    }

template<int PASS>
__global__ __launch_bounds__(64) void k_scan(const _Float16* __restrict__ pre,
                                             const float* __restrict__ Whh,
                                             const float* __restrict__ Wy,
                                             const float* __restrict__ by1,
                                             const float* __restrict__ by2,
                                             _Float16* __restrict__ prey,
                                             float* __restrict__ outf){
    int lane = threadIdx.x & 63;
    int q = lane >> 4, l15 = lane & 15;
    int n0 = blockIdx.x * 16;

    // A-tile mt, row m=l15 carries Whh row j'(mt,m) = (mt&1)*32+(m>>2)*8+(mt>>1)*4+(m&3)
    f16x8 Af[4][2];
#pragma unroll
    for (int mt = 0; mt < 4; mt++){
        int jrow = ((mt & 1) * 32) + ((l15 >> 2) * 8) + ((mt >> 1) * 4) + (l15 & 3);
#pragma unroll
        for (int kc = 0; kc < 2; kc++){
            const float* p = Whh + jrow * 64 + kc * 32 + q * 8;
#pragma unroll
            for (int i = 0; i < 8; i++) Af[mt][kc][i] = (_Float16)p[i];
        }
    }
    f16x8 Yf[4][2];
    f32x4 biasy[4];
    if constexpr (PASS == 0){
#pragma unroll
        for (int mt = 0; mt < 4; mt++){
            int jrow = ((mt & 1) * 32) + ((l15 >> 2) * 8) + ((mt >> 1) * 4) + (l15 & 3);
#pragma unroll
            for (int kc = 0; kc < 2; kc++){
                const float* p = Wy + jrow * 64 + kc * 32 + q * 8;
#pragma unroll
                for (int i = 0; i < 8; i++) Yf[mt][kc][i] = (_Float16)p[i];
            }
#pragma unroll
            for (int r = 0; r < 4; r++)
                biasy[mt][r] = by1[JST(mt) + r] + by2[JST(mt) + r];
        }
    }

    f16x8 Bf0, Bf1;
#pragma unroll
    for (int i = 0; i < 8; i++){ Bf0[i] = (_Float16)0.f; Bf1[i] = (_Float16)0.f; }

    int bb = n0 >> 7, low7 = n0 & 127;   // PASS0: h0 = low7; PASS1: w0 = low7

    const _Float16* pb = pre + (size_t)(n0 + l15) * 64;
    size_t spy = (size_t)(low7 + l15) * NSEQ + (size_t)bb * 128;  // PASS0 prey seq base

    f16x4 psA[4][4], psB[4][4];
    LOADSLAB(psA, 0);
    for (int gg = 0; gg < 16; gg++){
        LOADSLAB(psB, gg * 8 + 4);          // t <= 127, always in-bounds
        STEP4(psA, gg * 8);
        if (gg < 15) LOADSLAB(psA, gg * 8 + 8);
        STEP4(psB, gg * 8 + 4);
    }
    // tail: pre_y[127] from final B (= h_127)
    if constexpr (PASS == 0){
#pragma unroll
        for (int mt = 0; mt < 4; mt++){
            f32x4 y = biasy[mt];
            y = __builtin_amdgcn_mfma_f32_16x16x32_f16(Yf[mt][0], Bf0, y, 0, 0, 0);
            y = __builtin_amdgcn_mfma_f32_16x16x32_f16(Yf[mt][1], Bf1, y, 0, 0, 0);
            u16x4 pv;
#pragma unroll
            for (int r = 0; r < 4; r++) pv[r] = h2us((_Float16)y[r]);
            *(u16x4*)(prey + (spy + (TLEN - 1)) * 64 + JST(mt)) = pv;
        }
    }
}

// ---------------------------------------------------------------------------
extern "C" void kernel_launch(void* const* d_in, const int* in_sizes, int n_in,
                              void* d_out, int out_size, void* d_ws, size_t ws_size,
                              hipStream_t stream){
    (void)in_sizes; (void)n_in; (void)out_size; (void)ws_size;
    const float* x    = (const float*)d_in[0];
    const float* Wihx = (const float*)d_in[1];
    const float* Whhx = (const float*)d_in[2];
    const float* bihx = (const float*)d_in[3];
    const float* bhhx = (const float*)d_in[4];
    const float* Wihy = (const float*)d_in[5];
    const float* Whhy = (const float*)d_in[6];
    const float* bihy = (const float*)d_in[7];
    const float* bhhy = (const float*)d_in[8];
    _Float16* prex = (_Float16*)d_ws;                          // 33.5MB
    _Float16* prey = prex + (size_t)NSEQ * TLEN * 64;          // 33.5MB
    float* of = (float*)d_out;

    k_proj0 <<<2048, 256, 0, stream>>>(x, Wihx, bihx, bhhx, prex);
    k_scan<0><<<128, 64, 0, stream>>>(prex, Whhx, Wihy, bihy, bhhy, prey, nullptr);
    k_scan<1><<<128, 64, 0, stream>>>(prey, Whhy, nullptr, nullptr, nullptr, nullptr, of);
}